// Round 6
// baseline (9428.089 us; speedup 1.0000x reference)
//
#include <hip/hip_runtime.h>

#define T_STEPS 512
#define BATCH   32
#define DIM     256
#define UNITS   256
#define COLS4U  1024
#define NCAND   64

typedef _Float16 half8  __attribute__((ext_vector_type(8)));
typedef _Float16 half4v __attribute__((ext_vector_type(4)));
typedef float    f32x4  __attribute__((ext_vector_type(4)));
typedef unsigned uint4v __attribute__((ext_vector_type(4)));
typedef unsigned long long ull;
typedef ull      ull2   __attribute__((ext_vector_type(2)));

__device__ __forceinline__ float fsig(float x){ return 1.0f/(1.0f+__expf(-x)); }
__device__ __forceinline__ float ftanh(float x){
  float xx=fminf(fmaxf(x,-15.f),15.f);
  float e=__expf(2.f*xx);
  return (e-1.f)/(e+1.f);
}
// byte offset into a [32][256] f16 LDS plane, XOR-swizzled 16B granules
__device__ __forceinline__ int swz(int b,int u){
  int g=u>>3; int s=(g&7)^(b&7);
  return b*512 + (g>>3)*128 + s*16 + (u&7)*2;
}

// batched 8-word read, sc0 (bypass L1, read the XCD-shared L2)
__device__ __forceinline__ void ld8_sc0(const unsigned* p, uint4v& a, uint4v& b){
  asm volatile(
    "global_load_dwordx4 %0, %2, off sc0\n\t"
    "global_load_dwordx4 %1, %2, off offset:16 sc0\n\t"
    "s_waitcnt vmcnt(0)"
    : "=&v"(a), "=&v"(b) : "v"(p) : "memory");
}
// coherent (write-through) single-word store
__device__ __forceinline__ void st1_sc0(unsigned* p, unsigned v){
  asm volatile("global_store_dword %0, %1, off sc0" :: "v"(p), "v"(v) : "memory");
}

// ============================================================================
// Phase 1 (r3-proven, verbatim): xp[dir][t][col][b] fp16 = b + x@Wk
// ============================================================================
__global__ __launch_bounds__(256, 2) void xproj(
    const float* __restrict__ x,
    const float* __restrict__ Wk_f, const float* __restrict__ b_f,
    const float* __restrict__ Wk_b, const float* __restrict__ b_b,
    _Float16* __restrict__ xph)
{
  const int bx  = blockIdx.x;
  const int dir = bx >> 8;
  const int cg  = (bx >> 5) & 7;
  const int tg  = bx & 31;
  const int tid = threadIdx.x;
  const int w   = tid >> 6;
  const int lane= tid & 63;
  const int l15 = lane & 15;
  const int l4  = lane >> 4;

  const float* Wk = dir ? Wk_b : Wk_f;
  const float* bs = dir ? b_b  : b_f;

  const int col0 = cg*128 + w*32;

  half8 Bf[2][8];
  float bias[2];
#pragma unroll
  for (int nt=0; nt<2; nt++){
    const int col = col0 + nt*16 + l15;
    bias[nt] = bs[col];
#pragma unroll
    for (int kk=0; kk<8; kk++){
      half8 v;
#pragma unroll
      for (int r=0; r<8; r++) v[r] = (_Float16)Wk[(size_t)(kk*32 + l4*8 + r)*COLS4U + col];
      Bf[nt][kk] = v;
    }
  }

  for (int tt=0; tt<16; ++tt){
    const int t   = tg*16 + tt;
    const int tin = dir ? (T_STEPS-1-t) : t;

    half8 Af[2][8];
#pragma unroll
    for (int mt=0; mt<2; mt++){
      const int b = mt*16 + l15;
#pragma unroll
      for (int kk=0; kk<8; kk++){
        const float* xp_ = x + ((size_t)b*T_STEPS + tin)*DIM + kk*32 + l4*8;
        f32x4 u0 = *(const f32x4*)xp_;
        f32x4 u1 = *(const f32x4*)(xp_ + 4);
        half8 v;
        v[0]=(_Float16)u0[0]; v[1]=(_Float16)u0[1]; v[2]=(_Float16)u0[2]; v[3]=(_Float16)u0[3];
        v[4]=(_Float16)u1[0]; v[5]=(_Float16)u1[1]; v[6]=(_Float16)u1[2]; v[7]=(_Float16)u1[3];
        Af[mt][kk] = v;
      }
    }

    f32x4 acc[2][2];
#pragma unroll
    for (int nt=0; nt<2; nt++){
      f32x4 a; a[0]=bias[nt]; a[1]=bias[nt]; a[2]=bias[nt]; a[3]=bias[nt];
      acc[nt][0]=a; acc[nt][1]=a;
    }
#pragma unroll
    for (int kk=0; kk<8; kk++)
#pragma unroll
      for (int nt=0; nt<2; nt++)
#pragma unroll
        for (int mt=0; mt<2; mt++)
          acc[nt][mt] = __builtin_amdgcn_mfma_f32_16x16x32_f16(Af[mt][kk], Bf[nt][kk], acc[nt][mt], 0,0,0);

#pragma unroll
    for (int nt=0; nt<2; nt++){
      const int col = col0 + nt*16 + l15;
#pragma unroll
      for (int mt=0; mt<2; mt++){
        half4v o;
        o[0]=(_Float16)acc[nt][mt][0]; o[1]=(_Float16)acc[nt][mt][1];
        o[2]=(_Float16)acc[nt][mt][2]; o[3]=(_Float16)acc[nt][mt][3];
        *(ull*)(xph + ((size_t)(dir*T_STEPS + t)*COLS4U + col)*BATCH + mt*16 + l4*4)
            = __builtin_bit_cast(ull, o);
      }
    }
  }
}

// ============================================================================
// Phase 2: scan with DUAL publish (fast sc0 slice + safe agent-atomic slice).
// Readers try fast path; sticky-degrade per-thread to the safe (r3) path.
// ============================================================================
__device__ __forceinline__ void scan_body(
    int dir, int half_, bool fast0,
    const float* __restrict__ Wr, float* __restrict__ out,
    const _Float16* __restrict__ xph,
    unsigned* __restrict__ fastslc, unsigned* __restrict__ safeslc,
    _Float16 (*hlds)[BATCH*UNITS])
{
  const int tid  = threadIdx.x;
  const int w    = tid >> 6;
  const int lane = tid & 63;
  const int l15  = lane & 15;
  const int l4   = lane >> 4;

  const int uloc   = w*16 + l15;          // 0..127
  const int unit   = half_*128 + uloc;    // 0..255
  const int outcol = dir*256 + unit;

  half8 Bf[4][8];
#pragma unroll
  for (int q=0; q<4; q++){
    const int col = q*256 + unit;
#pragma unroll
    for (int kk=0; kk<8; kk++){
      half8 v;
#pragma unroll
      for (int r=0; r<8; r++) v[r] = (_Float16)Wr[(size_t)(kk*32 + l4*8 + r)*COLS4U + col];
      Bf[q][kk] = v;
      __builtin_amdgcn_sched_barrier(0);
    }
  }

  {
    half8 z;
#pragma unroll
    for (int e=0; e<8; e++) z[e] = (_Float16)0.f;
    for (int i=tid; i<BATCH*UNITS/8; i+=512) ((half8*)hlds[0])[i] = z;
  }
  __syncthreads();

  const int b_r = tid >> 4;            // 0..31
  const int c0  = (tid & 15) * 8;      // 0..120
  const int pbase = (1-half_)*128;

  float cst[8];
#pragma unroll
  for (int i=0;i<8;i++) cst[i]=0.f;
  bool use_fast = fast0;
  bool safe_ok  = true;

  ull xpv[8];
#pragma unroll
  for (int q=0;q<4;q++)
#pragma unroll
    for (int mt=0;mt<2;mt++)
      xpv[q*2+mt] = *(const ull*)(xph + ((size_t)(dir*T_STEPS + 0)*COLS4U + q*256+unit)*BATCH + mt*16 + l4*4);

  for (int t=0; t<T_STEPS; ++t){
    // ---- acc init from xp ----
    f32x4 acc[2][4];
#pragma unroll
    for (int q=0;q<4;q++)
#pragma unroll
      for (int mt=0;mt<2;mt++){
        half4v hv = __builtin_bit_cast(half4v, xpv[q*2+mt]);
        f32x4 a; a[0]=(float)hv[0]; a[1]=(float)hv[1]; a[2]=(float)hv[2]; a[3]=(float)hv[3];
        acc[mt][q] = a;
      }

    // ---- z += h_t @ Wr ----
    const char* hpl = (const char*)hlds[t&1];
#pragma unroll
    for (int kk=0; kk<8; kk++){
      const int ul = kk*32 + l4*8;
      half8 a0 = *(const half8*)(hpl + swz(l15,    ul));
      half8 a1 = *(const half8*)(hpl + swz(16+l15, ul));
#pragma unroll
      for (int q=0;q<4;q++){
        acc[0][q] = __builtin_amdgcn_mfma_f32_16x16x32_f16(a0, Bf[q][kk], acc[0][q], 0,0,0);
        acc[1][q] = __builtin_amdgcn_mfma_f32_16x16x32_f16(a1, Bf[q][kk], acc[1][q], 0,0,0);
      }
    }

    // ---- gates -> c,h ; dual publish + own LDS + out ----
    const int tout = dir ? (T_STEPS-1-t) : t;
    const int par  = (t+1) & 1;
    const size_t wslot = ((size_t)(par*4 + dir*2 + half_))*4096;
    const unsigned tgt = (unsigned)(t+1) & 0xFFFFu;
    char* hnx = (char*)hlds[(t+1)&1];
#pragma unroll
    for (int mt=0; mt<2; mt++){
#pragma unroll
      for (int r=0;r<4;r++){
        const int b = mt*16 + l4*4 + r;
        float iv = fsig (acc[mt][0][r]);
        float fv = fsig (acc[mt][1][r]);
        float gv = ftanh(acc[mt][2][r]);
        float ov = fsig (acc[mt][3][r]);
        float &c = cst[mt*4+r];
        c = fv*c + iv*gv;
        float hv = ov*ftanh(c);
        _Float16 hf = (_Float16)hv;
        if (t+1 < T_STEPS){
          unsigned word = ((unsigned)__builtin_bit_cast(unsigned short, hf) << 16) | tgt;
          st1_sc0(&fastslc[wslot + b*128 + uloc], word);
          __hip_atomic_store(&safeslc[wslot + b*128 + uloc], word,
                             __ATOMIC_RELAXED, __HIP_MEMORY_SCOPE_AGENT);
        }
        *(_Float16*)(hnx + swz(b, unit)) = hf;
        out[((size_t)b*T_STEPS + tout)*(2*UNITS) + outcol] = hv;
        if (t == T_STEPS-1)
          out[(size_t)BATCH*T_STEPS*(2*UNITS) + (size_t)b*(2*UNITS) + outcol] = hv;
      }
    }

    // ---- prefetch xp(t+1), read peer slice: fast then safe ----
    if (t+1 < T_STEPS){
#pragma unroll
      for (int q=0;q<4;q++)
#pragma unroll
        for (int mt=0;mt<2;mt++)
          xpv[q*2+mt] = *(const ull*)(xph + ((size_t)(dir*T_STEPS + (t+1))*COLS4U + q*256+unit)*BATCH + mt*16 + l4*4);

      const size_t rslot = ((size_t)(par*4 + dir*2 + (1-half_)))*4096;
      const unsigned* fsrc = fastslc + rslot + b_r*128 + c0;
      const unsigned* ssrc = safeslc + rslot + b_r*128 + c0;
      unsigned wv[8];
      bool got = false;

      if (use_fast){
        int sp = 0;
        for(;;){
          uint4v a, b2;
          ld8_sc0(fsrc, a, b2);
          wv[0]=a[0]; wv[1]=a[1]; wv[2]=a[2]; wv[3]=a[3];
          wv[4]=b2[0]; wv[5]=b2[1]; wv[6]=b2[2]; wv[7]=b2[3];
          bool ok = true;
#pragma unroll
          for (int k=0;k<8;k++) ok &= ((wv[k]&0xFFFFu)==tgt);
          if (ok){ got = true; break; }
          if (++sp > 4096){ use_fast = false; break; }   // sticky degrade
        }
      }
      if (!got){
        if (safe_ok){
          int sp = 0;
          for(;;){
            bool ok = true;
#pragma unroll
            for (int k=0;k<8;k++){
              wv[k] = __hip_atomic_load(ssrc+k, __ATOMIC_RELAXED, __HIP_MEMORY_SCOPE_AGENT);
              ok &= ((wv[k]&0xFFFFu)==tgt);
            }
            if (ok) break;
            if (++sp > (1<<20)){ safe_ok = false; break; }   // never hang
          }
        } else {
#pragma unroll
          for (int k=0;k<8;k++)
            wv[k] = __hip_atomic_load(ssrc+k, __ATOMIC_RELAXED, __HIP_MEMORY_SCOPE_AGENT);
        }
      }

      half8 hh;
#pragma unroll
      for (int e=0;e<8;e++)
        hh[e] = __builtin_bit_cast(_Float16,(unsigned short)(wv[e]>>16));
      *(half8*)(hnx + swz(b_r, pbase + c0)) = hh;
    }
    __syncthreads();
  }
}

__global__ __launch_bounds__(512,1) void bilstm_scan_pair(
    const float* __restrict__ Wr_f, const float* __restrict__ Wr_b,
    float* __restrict__ out, const _Float16* __restrict__ xph,
    unsigned* __restrict__ fastslc, unsigned* __restrict__ safeslc,
    unsigned* __restrict__ regtab)
{
  __shared__ _Float16 hlds[2][BATCH*UNITS];
  __shared__ unsigned stab[NCAND];
  __shared__ int sinfo[2];
  const int tid = threadIdx.x;
  const int bid = (int)blockIdx.x;

  // ---- register this block's XCD ----
  if (tid==0){
    unsigned xv;
    asm volatile("s_getreg_b32 %0, hwreg(HW_REG_XCC_ID)":"=s"(xv));
    __hip_atomic_store(&regtab[bid], 0x100u|(xv&0xFu),
                       __ATOMIC_RELAXED,__HIP_MEMORY_SCOPE_AGENT);
  }

  // ---- block 0: single decider ----
  if (bid==0){
    if (tid<NCAND){
      unsigned v; int sp=0;
      for(;;){
        v=__hip_atomic_load(&regtab[tid],__ATOMIC_RELAXED,__HIP_MEMORY_SCOPE_AGENT);
        if (__all((v&0x100u)!=0u)) break;
        if (++sp>(1<<18)) break;
      }
      stab[tid]=v;
    }
    __syncthreads();
    if (tid==0){
      bool full=true;
      for (int i=0;i<NCAND;i++) if(!(stab[i]&0x100u)){full=false;break;}
      unsigned dec;
      int xs=-1;
      if (full){
        int cnt[16];
        for (int a=0;a<16;a++) cnt[a]=0;
        for (int i=0;i<NCAND;i++) cnt[stab[i]&0xF]++;
        for (int a=0;a<16;a++) if (cnt[a]>=4){xs=a;break;}
      }
      if (xs>=0){
        unsigned ids[4]; int n=0;
        for (int i=0;i<NCAND && n<4;i++) if ((int)(stab[i]&0xF)==xs) ids[n++]=(unsigned)i;
        dec = 0x80000000u | (ids[0]) | (ids[1]<<6) | (ids[2]<<12) | (ids[3]<<18);
      } else {
        dec = 0x80000000u | (1u<<30) | 0u | (1u<<6) | (2u<<12) | (3u<<18);
      }
      __hip_atomic_store(&regtab[NCAND], dec, __ATOMIC_RELAXED,__HIP_MEMORY_SCOPE_AGENT);
    }
  }

  // ---- all blocks: poll the decision; timeout -> deterministic safe roles ----
  if (tid==0){
    unsigned dec=0; int sp=0;
    for(;;){
      dec=__hip_atomic_load(&regtab[NCAND],__ATOMIC_RELAXED,__HIP_MEMORY_SCOPE_AGENT);
      if (dec & 0x80000000u) break;
      if (++sp>(1<<22)){ dec = 0x80000000u|(1u<<30)|0u|(1u<<6)|(2u<<12)|(3u<<18); break; }
    }
    int role=-1;
    const int mode = (int)((dec>>30)&1u);
#pragma unroll
    for (int i=0;i<4;i++) if (((dec>>(6*i))&63u)==(unsigned)bid) role=i;
    sinfo[0]=role; sinfo[1]=mode;
  }
  __syncthreads();
  const int role=sinfo[0];
  if (role<0) return;
  const int dir=role>>1, hf=role&1;
  const float* Wr = dir ? Wr_b : Wr_f;
  scan_body(dir, hf, sinfo[1]==0, Wr, out, xph, fastslc, safeslc, hlds);
}

// ============================================================================
// Fallback for small ws (round-2 proven fused kernel)
// ============================================================================
__global__ __launch_bounds__(256,1) void bilstm_mfma(
    const float* __restrict__ x,
    const float* __restrict__ Wk_f, const float* __restrict__ Wr_f, const float* __restrict__ b_f,
    const float* __restrict__ Wk_b, const float* __restrict__ Wr_b, const float* __restrict__ b_b,
    float* __restrict__ out,
    unsigned short* __restrict__ slices,
    unsigned* __restrict__ flags)
{
  const int dir = blockIdx.x >> 2;
  const int g4  = blockIdx.x & 3;
  const int tid = threadIdx.x;
  const int w   = tid >> 6;
  const int lane= tid & 63;
  const int l15 = lane & 15;
  const int l4  = lane >> 4;

  const float* Wk = dir ? Wk_b : Wk_f;
  const float* Wr = dir ? Wr_b : Wr_f;
  const float* bs = dir ? b_b  : b_f;

  const int u0b   = g4*64;
  const int upl   = u0b + w*16 + l15;
  const int outcol= dir*256 + upl;

  __shared__ _Float16 xlds[BATCH*DIM];
  __shared__ _Float16 hlds[2][BATCH*UNITS];

  half8 Bf[4][16];
#pragma unroll
  for (int q=0;q<4;q++){
    const int col = q*256 + upl;
#pragma unroll
    for (int kk=0;kk<16;kk++){
      const float* Ws = (kk<8) ? Wk : Wr;
      const int k0 = (kk&7)*32 + l4*8;
      half8 v;
#pragma unroll
      for (int r=0;r<8;r++) v[r] = (_Float16)Ws[(size_t)(k0+r)*COLS4U + col];
      Bf[q][kk] = v;
      __builtin_amdgcn_sched_barrier(0);
    }
  }

  float bias[4];
#pragma unroll
  for (int q=0;q<4;q++) bias[q] = bs[q*256 + upl];

  {
    half8 z;
#pragma unroll
    for (int e=0;e<8;e++) z[e] = (_Float16)0.f;
    for (int i=tid; i<BATCH*UNITS/8; i+=256) ((half8*)hlds[0])[i] = z;
  }

  const int bx  = tid >> 3;
  const int d0x = (tid & 7) * 32;
  float xr[32];
  {
    const int tin0 = dir ? (T_STEPS-1) : 0;
    const float* xp = x + ((size_t)bx*T_STEPS + tin0)*DIM + d0x;
#pragma unroll
    for (int i=0;i<8;i++){
      f32x4 v = *(const f32x4*)(xp + i*4);
      xr[i*4+0]=v[0]; xr[i*4+1]=v[1]; xr[i*4+2]=v[2]; xr[i*4+3]=v[3];
    }
#pragma unroll
    for (int j=0;j<4;j++){
      half8 hh;
#pragma unroll
      for (int e=0;e<8;e++) hh[e] = (_Float16)xr[j*8+e];
      *(half8*)((char*)xlds + swz(bx, d0x + j*8)) = hh;
    }
  }
  __syncthreads();

  float cst[8];
#pragma unroll
  for (int i=0;i<8;i++) cst[i]=0.f;
  bool spin_ok = true;

  for (int t=0; t<T_STEPS; ++t){
    if (t+1 < T_STEPS){
      const int tin = dir ? (T_STEPS-2-t) : (t+1);
      const float* xp = x + ((size_t)bx*T_STEPS + tin)*DIM + d0x;
#pragma unroll
      for (int i=0;i<8;i++){
        f32x4 v = *(const f32x4*)(xp + i*4);
        xr[i*4+0]=v[0]; xr[i*4+1]=v[1]; xr[i*4+2]=v[2]; xr[i*4+3]=v[3];
      }
    }

    f32x4 acc[2][4];
#pragma unroll
    for (int q=0;q<4;q++){
      f32x4 a; a[0]=bias[q]; a[1]=bias[q]; a[2]=bias[q]; a[3]=bias[q];
      acc[0][q]=a; acc[1][q]=a;
    }
    const char* hpl = (const char*)hlds[t&1];
#pragma unroll
    for (int kk=0;kk<16;kk++){
      const char* pl = (kk<8) ? (const char*)xlds : hpl;
      const int ul = (kk&7)*32 + l4*8;
      half8 a0 = *(const half8*)(pl + swz(l15,      ul));
      half8 a1 = *(const half8*)(pl + swz(16+l15,   ul));
#pragma unroll
      for (int q=0;q<4;q++){
        acc[0][q] = __builtin_amdgcn_mfma_f32_16x16x32_f16(a0, Bf[q][kk], acc[0][q], 0,0,0);
        acc[1][q] = __builtin_amdgcn_mfma_f32_16x16x32_f16(a1, Bf[q][kk], acc[1][q], 0,0,0);
      }
    }

    const int tout = dir ? (T_STEPS-1-t) : t;
    unsigned short* slc = slices + (((size_t)((t+1)&1))*8 + dir*4 + g4)*2048;
    char* hnx = (char*)hlds[(t+1)&1];
#pragma unroll
    for (int mt=0; mt<2; mt++){
#pragma unroll
      for (int r=0;r<4;r++){
        const int b = mt*16 + l4*4 + r;
        float iv = fsig (acc[mt][0][r]);
        float fv = fsig (acc[mt][1][r]);
        float gv = ftanh(acc[mt][2][r]);
        float ov = fsig (acc[mt][3][r]);
        float &c = cst[mt*4+r];
        c = fv*c + iv*gv;
        float hval = ov*ftanh(c);
        out[((size_t)b*T_STEPS + tout)*(2*UNITS) + outcol] = hval;
        if (t == T_STEPS-1)
          out[(size_t)BATCH*T_STEPS*(2*UNITS) + (size_t)b*(2*UNITS) + outcol] = hval;
        _Float16 hf = (_Float16)hval;
        *(_Float16*)(hnx + swz(b, upl)) = hf;
        if (t+1 < T_STEPS)
          __hip_atomic_store(&slc[b*64 + (w*16+l15)],
                             __builtin_bit_cast(unsigned short, hf),
                             __ATOMIC_RELAXED, __HIP_MEMORY_SCOPE_AGENT);
      }
    }
    __syncthreads();

    if (t+1 < T_STEPS){
      if (tid == 192)
        __hip_atomic_store(&flags[(dir*4+g4)*32], (unsigned)(t+1),
                           __ATOMIC_RELAXED, __HIP_MEMORY_SCOPE_AGENT);
#pragma unroll
      for (int j=0;j<4;j++){
        half8 hh;
#pragma unroll
        for (int e=0;e<8;e++) hh[e] = (_Float16)xr[j*8+e];
        *(half8*)((char*)xlds + swz(bx, d0x + j*8)) = hh;
      }
      if (w < 3){
        const int p = w + (w >= g4);
        const unsigned target = (unsigned)(t+1);
        if (spin_ok){
          int sp = 0;
          while (__hip_atomic_load(&flags[(dir*4+p)*32],
                                   __ATOMIC_RELAXED, __HIP_MEMORY_SCOPE_AGENT) < target){
            if (++sp > (1<<22)) { spin_ok = false; break; }
          }
        }
        const ull* src = (const ull*)(slices + (((size_t)((t+1)&1))*8 + dir*4 + p)*2048);
        const int bsl = lane >> 1;
        const int u00 = (lane & 1) * 32;
#pragma unroll
        for (int j=0;j<4;j++){
          ull v0 = __hip_atomic_load(&src[lane*8 + 2*j  ], __ATOMIC_RELAXED, __HIP_MEMORY_SCOPE_AGENT);
          ull v1 = __hip_atomic_load(&src[lane*8 + 2*j+1], __ATOMIC_RELAXED, __HIP_MEMORY_SCOPE_AGENT);
          ull2 vv; vv[0]=v0; vv[1]=v1;
          *(ull2*)(hnx + swz(bsl, p*64 + u00 + j*8)) = vv;
        }
      }
      __syncthreads();
    }
  }
}

extern "C" void kernel_launch(void* const* d_in, const int* in_sizes, int n_in,
                              void* d_out, int out_size, void* d_ws, size_t ws_size,
                              hipStream_t stream) {
  const float* x    = (const float*)d_in[0];
  const float* Wk_f = (const float*)d_in[1];
  const float* Wr_f = (const float*)d_in[2];
  const float* b_f  = (const float*)d_in[3];
  const float* Wk_b = (const float*)d_in[4];
  const float* Wr_b = (const float*)d_in[5];
  const float* b_b  = (const float*)d_in[6];
  float* out = (float*)d_out;

  const size_t XPH  = (size_t)2*T_STEPS*COLS4U*BATCH*sizeof(_Float16);  // 64 MiB
  const size_t SL   = (size_t)8*4096*sizeof(unsigned);                  // 128 KiB each
  const size_t RT   = 512;

  if (ws_size >= XPH + 2*SL + RT) {
    _Float16* xph     = (_Float16*)d_ws;
    unsigned* fastslc = (unsigned*)((char*)d_ws + XPH);
    unsigned* safeslc = (unsigned*)((char*)d_ws + XPH + SL);
    unsigned* regtab  = (unsigned*)((char*)d_ws + XPH + 2*SL);
    // zero fast+safe slices (tags) + regtab (election) each launch — replay-safe
    hipMemsetAsync((char*)d_ws + XPH, 0, 2*SL + RT, stream);
    xproj<<<512, 256, 0, stream>>>(x, Wk_f, b_f, Wk_b, b_b, xph);
    bilstm_scan_pair<<<NCAND, 512, 0, stream>>>(Wr_f, Wr_b, out, xph,
                                                fastslc, safeslc, regtab);
  } else {
    unsigned short* slices = (unsigned short*)d_ws;
    unsigned* flags = (unsigned*)((char*)d_ws + 65536);
    hipMemsetAsync((char*)d_ws + 65536, 0, 1024, stream);
    bilstm_mfma<<<8, 256, 0, stream>>>(x, Wk_f, Wr_f, b_f, Wk_b, Wr_b, b_b,
                                       out, slices, flags);
  }
}

// Round 7
// 8672.118 us; speedup vs baseline: 1.0872x; 1.0872x over previous
//
#include <hip/hip_runtime.h>

#define T_STEPS 512
#define BATCH   32
#define DIM     256
#define UNITS   256
#define COLS4U  1024

typedef _Float16 half8  __attribute__((ext_vector_type(8)));
typedef _Float16 half4v __attribute__((ext_vector_type(4)));
typedef float    f32x4  __attribute__((ext_vector_type(4)));
typedef unsigned long long ull;
typedef ull      ull2   __attribute__((ext_vector_type(2)));

__device__ __forceinline__ float fsig(float x){ return 1.0f/(1.0f+__expf(-x)); }
__device__ __forceinline__ float ftanh(float x){
  float xx=fminf(fmaxf(x,-15.f),15.f);
  float e=__expf(2.f*xx);
  return (e-1.f)/(e+1.f);
}
// byte offset into a [32][256] f16 LDS plane, XOR-swizzled 16B granules (proven r2/r3)
__device__ __forceinline__ int swz(int b,int u){
  int g=u>>3; int s=(g&7)^(b&7);
  return b*512 + (g>>3)*128 + s*16 + (u&7)*2;
}
// granule index of the (col, l4) weight fragment within one kt-plane (4096 granules).
// XOR spreads the 4-q / 16-col read pattern across all 8 LDS bank-quartets; bijective.
__device__ __forceinline__ int gran(int col,int q){
  return ((col<<2) | q) ^ ((col>>1)&7);
}

// ============================================================================
// repack: rp[dir][kt 0..7][granule 0..4095][8 halfs] = Wr fragment
//   fragment(col, kt, q=l4) = Wr[kt*32+q*8 .. +8][col] as fp16
// ============================================================================
__global__ __launch_bounds__(256) void repack(
    const float* __restrict__ Wr_f, const float* __restrict__ Wr_b,
    _Float16* __restrict__ rp)
{
  const int idx = blockIdx.x*256 + threadIdx.x;   // 65536 total
  const int q   = idx & 3;
  const int col = (idx>>2) & 1023;
  const int kt  = (idx>>12) & 7;
  const int dir = idx >> 15;
  const float* Wr = dir ? Wr_b : Wr_f;
  half8 v;
#pragma unroll
  for (int r=0;r<8;r++) v[r] = (_Float16)Wr[(size_t)(kt*32 + q*8 + r)*COLS4U + col];
  *(half8*)(rp + ((size_t)((dir*8 + kt)*4096 + gran(col,q)) << 3)) = v;
}

// ============================================================================
// Phase 1 (r3-proven, verbatim): xp[dir][t][col][b] fp16 = b + x@Wk
// ============================================================================
__global__ __launch_bounds__(256, 2) void xproj(
    const float* __restrict__ x,
    const float* __restrict__ Wk_f, const float* __restrict__ b_f,
    const float* __restrict__ Wk_b, const float* __restrict__ b_b,
    _Float16* __restrict__ xph)
{
  const int bx  = blockIdx.x;
  const int dir = bx >> 8;
  const int cg  = (bx >> 5) & 7;
  const int tg  = bx & 31;
  const int tid = threadIdx.x;
  const int w   = tid >> 6;
  const int lane= tid & 63;
  const int l15 = lane & 15;
  const int l4  = lane >> 4;

  const float* Wk = dir ? Wk_b : Wk_f;
  const float* bs = dir ? b_b  : b_f;

  const int col0 = cg*128 + w*32;

  half8 Bf[2][8];
  float bias[2];
#pragma unroll
  for (int nt=0; nt<2; nt++){
    const int col = col0 + nt*16 + l15;
    bias[nt] = bs[col];
#pragma unroll
    for (int kk=0; kk<8; kk++){
      half8 v;
#pragma unroll
      for (int r=0; r<8; r++) v[r] = (_Float16)Wk[(size_t)(kk*32 + l4*8 + r)*COLS4U + col];
      Bf[nt][kk] = v;
    }
  }

  for (int tt=0; tt<16; ++tt){
    const int t   = tg*16 + tt;
    const int tin = dir ? (T_STEPS-1-t) : t;

    half8 Af[2][8];
#pragma unroll
    for (int mt=0; mt<2; mt++){
      const int b = mt*16 + l15;
#pragma unroll
      for (int kk=0; kk<8; kk++){
        const float* xp_ = x + ((size_t)b*T_STEPS + tin)*DIM + kk*32 + l4*8;
        f32x4 u0 = *(const f32x4*)xp_;
        f32x4 u1 = *(const f32x4*)(xp_ + 4);
        half8 v;
        v[0]=(_Float16)u0[0]; v[1]=(_Float16)u0[1]; v[2]=(_Float16)u0[2]; v[3]=(_Float16)u0[3];
        v[4]=(_Float16)u1[0]; v[5]=(_Float16)u1[1]; v[6]=(_Float16)u1[2]; v[7]=(_Float16)u1[3];
        Af[mt][kk] = v;
      }
    }

    f32x4 acc[2][2];
#pragma unroll
    for (int nt=0; nt<2; nt++){
      f32x4 a; a[0]=bias[nt]; a[1]=bias[nt]; a[2]=bias[nt]; a[3]=bias[nt];
      acc[nt][0]=a; acc[nt][1]=a;
    }
#pragma unroll
    for (int kk=0; kk<8; kk++)
#pragma unroll
      for (int nt=0; nt<2; nt++)
#pragma unroll
        for (int mt=0; mt<2; mt++)
          acc[nt][mt] = __builtin_amdgcn_mfma_f32_16x16x32_f16(Af[mt][kk], Bf[nt][kk], acc[nt][mt], 0,0,0);

#pragma unroll
    for (int nt=0; nt<2; nt++){
      const int col = col0 + nt*16 + l15;
#pragma unroll
      for (int mt=0; mt<2; mt++){
        half4v o;
        o[0]=(_Float16)acc[nt][mt][0]; o[1]=(_Float16)acc[nt][mt][1];
        o[2]=(_Float16)acc[nt][mt][2]; o[3]=(_Float16)acc[nt][mt][3];
        *(ull*)(xph + ((size_t)(dir*T_STEPS + t)*COLS4U + col)*BATCH + mt*16 + l4*4)
            = __builtin_bit_cast(ull, o);
      }
    }
  }
}

// ============================================================================
// Phase 2: whole direction on ONE CU. 1 block/dir, 512 thr (8 waves),
// 32 units/wave (8 ntiles: nt = gate*2 + un). Wr tiers:
//   kt 0..2 -> registers (Bf, 96 VGPR)  kt 3..4 -> LDS stash (128 KB)
//   kt 5..7 -> streamed from L2 each step (weights constant -> off serial path)
// h exchange = LDS + __syncthreads. No inter-block communication at all.
// ============================================================================
__global__ __launch_bounds__(512, 2) void bilstm_1cu(
    const _Float16* __restrict__ rp,
    float* __restrict__ out,
    const _Float16* __restrict__ xph)
{
  const int dir = (int)blockIdx.x;
  const int tid = threadIdx.x;
  const int w   = tid >> 6;         // 0..7
  const int lane= tid & 63;
  const int l15 = lane & 15;
  const int l4  = lane >> 4;

  __shared__ _Float16 stash[2*4096*8];   // 131072 B : kt3..4 fragments
  __shared__ _Float16 hpl[BATCH*UNITS];  // 16384 B  : single h plane (swizzled)

  int col[8];
#pragma unroll
  for (int nt=0; nt<8; nt++)
    col[nt] = (nt>>1)*256 + w*32 + (nt&1)*16 + l15;   // gate=nt>>1, un=nt&1

  const _Float16* rpd = rp + ((size_t)dir*8*4096 << 3);

  // --- one-time: reg fragments kt0..2 ---
  half8 Bf[8][3];
#pragma unroll
  for (int nt=0; nt<8; nt++)
#pragma unroll
    for (int kt=0; kt<3; kt++)
      Bf[nt][kt] = *(const half8*)(rpd + ((size_t)(kt*4096 + gran(col[nt],l4)) << 3));

  // --- one-time: stash fill kt3..4 (verbatim granule copy) ---
  for (int i=tid; i<8192; i+=512)
    *(ull2*)(stash + ((size_t)i<<3)) = *(const ull2*)(rpd + ((size_t)(3*4096 + i) << 3));

  // --- h=0 ---
  for (int i=tid; i<2048; i+=512) ((ull*)hpl)[i] = 0ull;
  __syncthreads();

  float cst[16];
#pragma unroll
  for (int i=0;i<16;i++) cst[i]=0.f;

  const _Float16* xpt = xph + (size_t)dir*T_STEPS*COLS4U*BATCH;

  for (int t=0; t<T_STEPS; ++t){
    // ---- acc init from xp (bias + x@Wk folded in) ----
    f32x4 acc[2][8];
#pragma unroll
    for (int mt=0; mt<2; mt++)
#pragma unroll
      for (int nt=0; nt<8; nt++){
        ull xv = *(const ull*)(xpt + (size_t)t*32768 + col[nt]*32 + mt*16 + l4*4);
        half4v hv = __builtin_bit_cast(half4v, xv);
        f32x4 a; a[0]=(float)hv[0]; a[1]=(float)hv[1]; a[2]=(float)hv[2]; a[3]=(float)hv[3];
        acc[mt][nt] = a;
      }

    // ---- issue stream kt5 ----
    half8 SA[8], SB[8];
#pragma unroll
    for (int nt=0; nt<8; nt++)
      SA[nt] = *(const half8*)(rpd + ((size_t)(5*4096 + gran(col[nt],l4)) << 3));

    // ---- reg ktiles 0..2 ----
#pragma unroll
    for (int kt=0; kt<3; kt++){
      const int ul = kt*32 + l4*8;
      half8 a0 = *(const half8*)((const char*)hpl + swz(l15,    ul));
      half8 a1 = *(const half8*)((const char*)hpl + swz(16+l15, ul));
#pragma unroll
      for (int nt=0; nt<8; nt++){
        acc[0][nt] = __builtin_amdgcn_mfma_f32_16x16x32_f16(a0, Bf[nt][kt], acc[0][nt], 0,0,0);
        acc[1][nt] = __builtin_amdgcn_mfma_f32_16x16x32_f16(a1, Bf[nt][kt], acc[1][nt], 0,0,0);
      }
    }

    // ---- stash ktiles 3..4 ----
#pragma unroll
    for (int ks=0; ks<2; ks++){
      const int kt = 3 + ks;
      const int ul = kt*32 + l4*8;
      half8 a0 = *(const half8*)((const char*)hpl + swz(l15,    ul));
      half8 a1 = *(const half8*)((const char*)hpl + swz(16+l15, ul));
#pragma unroll
      for (int nt=0; nt<8; nt++){
        half8 bs = *(const half8*)(stash + ((size_t)(ks*4096 + gran(col[nt],l4)) << 3));
        acc[0][nt] = __builtin_amdgcn_mfma_f32_16x16x32_f16(a0, bs, acc[0][nt], 0,0,0);
        acc[1][nt] = __builtin_amdgcn_mfma_f32_16x16x32_f16(a1, bs, acc[1][nt], 0,0,0);
      }
    }

    // ---- streamed ktiles 5..7 (double-buffered issue) ----
    {
      // kt5: issue kt6, consume SA
#pragma unroll
      for (int nt=0; nt<8; nt++)
        SB[nt] = *(const half8*)(rpd + ((size_t)(6*4096 + gran(col[nt],l4)) << 3));
      {
        const int ul = 5*32 + l4*8;
        half8 a0 = *(const half8*)((const char*)hpl + swz(l15,    ul));
        half8 a1 = *(const half8*)((const char*)hpl + swz(16+l15, ul));
#pragma unroll
        for (int nt=0; nt<8; nt++){
          acc[0][nt] = __builtin_amdgcn_mfma_f32_16x16x32_f16(a0, SA[nt], acc[0][nt], 0,0,0);
          acc[1][nt] = __builtin_amdgcn_mfma_f32_16x16x32_f16(a1, SA[nt], acc[1][nt], 0,0,0);
        }
      }
      // kt6: issue kt7, consume SB
#pragma unroll
      for (int nt=0; nt<8; nt++)
        SA[nt] = *(const half8*)(rpd + ((size_t)(7*4096 + gran(col[nt],l4)) << 3));
      {
        const int ul = 6*32 + l4*8;
        half8 a0 = *(const half8*)((const char*)hpl + swz(l15,    ul));
        half8 a1 = *(const half8*)((const char*)hpl + swz(16+l15, ul));
#pragma unroll
        for (int nt=0; nt<8; nt++){
          acc[0][nt] = __builtin_amdgcn_mfma_f32_16x16x32_f16(a0, SB[nt], acc[0][nt], 0,0,0);
          acc[1][nt] = __builtin_amdgcn_mfma_f32_16x16x32_f16(a1, SB[nt], acc[1][nt], 0,0,0);
        }
      }
      // kt7: consume SA
      {
        const int ul = 7*32 + l4*8;
        half8 a0 = *(const half8*)((const char*)hpl + swz(l15,    ul));
        half8 a1 = *(const half8*)((const char*)hpl + swz(16+l15, ul));
#pragma unroll
        for (int nt=0; nt<8; nt++){
          acc[0][nt] = __builtin_amdgcn_mfma_f32_16x16x32_f16(a0, SA[nt], acc[0][nt], 0,0,0);
          acc[1][nt] = __builtin_amdgcn_mfma_f32_16x16x32_f16(a1, SA[nt], acc[1][nt], 0,0,0);
        }
      }
    }

    __syncthreads();   // all waves done reading h_t from hpl

    // ---- gates -> c, h ; write h_{t+1} to hpl + out stores ----
    const int tout = dir ? (T_STEPS-1-t) : t;
#pragma unroll
    for (int un=0; un<2; un++){
      const int unit = w*32 + un*16 + l15;
      const int oc   = dir*256 + unit;
#pragma unroll
      for (int mt=0; mt<2; mt++){
#pragma unroll
        for (int r=0; r<4; r++){
          const int b = mt*16 + l4*4 + r;
          float iv = fsig (acc[mt][0+un][r]);
          float fv = fsig (acc[mt][2+un][r]);
          float gv = ftanh(acc[mt][4+un][r]);
          float ov = fsig (acc[mt][6+un][r]);
          float &c = cst[(mt*2+un)*4 + r];
          c = fv*c + iv*gv;
          float hv = ov*ftanh(c);
          if (t+1 < T_STEPS)
            *(_Float16*)((char*)hpl + swz(b, unit)) = (_Float16)hv;
          out[((size_t)b*T_STEPS + tout)*(2*UNITS) + oc] = hv;
          if (t == T_STEPS-1)
            out[(size_t)BATCH*T_STEPS*(2*UNITS) + (size_t)b*(2*UNITS) + oc] = hv;
        }
      }
    }
    __syncthreads();   // h_{t+1} complete before next step's reads
  }
}

// ============================================================================
// Fallback for small ws (round-2 proven fused kernel)
// ============================================================================
__global__ __launch_bounds__(256,1) void bilstm_mfma(
    const float* __restrict__ x,
    const float* __restrict__ Wk_f, const float* __restrict__ Wr_f, const float* __restrict__ b_f,
    const float* __restrict__ Wk_b, const float* __restrict__ Wr_b, const float* __restrict__ b_b,
    float* __restrict__ out,
    unsigned short* __restrict__ slices,
    unsigned* __restrict__ flags)
{
  const int dir = blockIdx.x >> 2;
  const int g4  = blockIdx.x & 3;
  const int tid = threadIdx.x;
  const int w   = tid >> 6;
  const int lane= tid & 63;
  const int l15 = lane & 15;
  const int l4  = lane >> 4;

  const float* Wk = dir ? Wk_b : Wk_f;
  const float* Wr = dir ? Wr_b : Wr_f;
  const float* bs = dir ? b_b  : b_f;

  const int u0b   = g4*64;
  const int upl   = u0b + w*16 + l15;
  const int outcol= dir*256 + upl;

  __shared__ _Float16 xlds[BATCH*DIM];
  __shared__ _Float16 hlds[2][BATCH*UNITS];

  half8 Bf[4][16];
#pragma unroll
  for (int q=0;q<4;q++){
    const int col = q*256 + upl;
#pragma unroll
    for (int kk=0;kk<16;kk++){
      const float* Ws = (kk<8) ? Wk : Wr;
      const int k0 = (kk&7)*32 + l4*8;
      half8 v;
#pragma unroll
      for (int r=0;r<8;r++) v[r] = (_Float16)Ws[(size_t)(k0+r)*COLS4U + col];
      Bf[q][kk] = v;
      __builtin_amdgcn_sched_barrier(0);
    }
  }

  float bias[4];
#pragma unroll
  for (int q=0;q<4;q++) bias[q] = bs[q*256 + upl];

  {
    half8 z;
#pragma unroll
    for (int e=0;e<8;e++) z[e] = (_Float16)0.f;
    for (int i=tid; i<BATCH*UNITS/8; i+=256) ((half8*)hlds[0])[i] = z;
  }

  const int bx  = tid >> 3;
  const int d0x = (tid & 7) * 32;
  float xr[32];
  {
    const int tin0 = dir ? (T_STEPS-1) : 0;
    const float* xp = x + ((size_t)bx*T_STEPS + tin0)*DIM + d0x;
#pragma unroll
    for (int i=0;i<8;i++){
      f32x4 v = *(const f32x4*)(xp + i*4);
      xr[i*4+0]=v[0]; xr[i*4+1]=v[1]; xr[i*4+2]=v[2]; xr[i*4+3]=v[3];
    }
#pragma unroll
    for (int j=0;j<4;j++){
      half8 hh;
#pragma unroll
      for (int e=0;e<8;e++) hh[e] = (_Float16)xr[j*8+e];
      *(half8*)((char*)xlds + swz(bx, d0x + j*8)) = hh;
    }
  }
  __syncthreads();

  float cst[8];
#pragma unroll
  for (int i=0;i<8;i++) cst[i]=0.f;
  bool spin_ok = true;

  for (int t=0; t<T_STEPS; ++t){
    if (t+1 < T_STEPS){
      const int tin = dir ? (T_STEPS-2-t) : (t+1);
      const float* xp = x + ((size_t)bx*T_STEPS + tin)*DIM + d0x;
#pragma unroll
      for (int i=0;i<8;i++){
        f32x4 v = *(const f32x4*)(xp + i*4);
        xr[i*4+0]=v[0]; xr[i*4+1]=v[1]; xr[i*4+2]=v[2]; xr[i*4+3]=v[3];
      }
    }

    f32x4 acc[2][4];
#pragma unroll
    for (int q=0;q<4;q++){
      f32x4 a; a[0]=bias[q]; a[1]=bias[q]; a[2]=bias[q]; a[3]=bias[q];
      acc[0][q]=a; acc[1][q]=a;
    }
    const char* hpl2 = (const char*)hlds[t&1];
#pragma unroll
    for (int kk=0;kk<16;kk++){
      const char* pl = (kk<8) ? (const char*)xlds : hpl2;
      const int ul = (kk&7)*32 + l4*8;
      half8 a0 = *(const half8*)(pl + swz(l15,      ul));
      half8 a1 = *(const half8*)(pl + swz(16+l15,   ul));
#pragma unroll
      for (int q=0;q<4;q++){
        acc[0][q] = __builtin_amdgcn_mfma_f32_16x16x32_f16(a0, Bf[q][kk], acc[0][q], 0,0,0);
        acc[1][q] = __builtin_amdgcn_mfma_f32_16x16x32_f16(a1, Bf[q][kk], acc[1][q], 0,0,0);
      }
    }

    const int tout = dir ? (T_STEPS-1-t) : t;
    unsigned short* slc = slices + (((size_t)((t+1)&1))*8 + dir*4 + g4)*2048;
    char* hnx = (char*)hlds[(t+1)&1];
#pragma unroll
    for (int mt=0; mt<2; mt++){
#pragma unroll
      for (int r=0;r<4;r++){
        const int b = mt*16 + l4*4 + r;
        float iv = fsig (acc[mt][0][r]);
        float fv = fsig (acc[mt][1][r]);
        float gv = ftanh(acc[mt][2][r]);
        float ov = fsig (acc[mt][3][r]);
        float &c = cst[mt*4+r];
        c = fv*c + iv*gv;
        float hval = ov*ftanh(c);
        out[((size_t)b*T_STEPS + tout)*(2*UNITS) + outcol] = hval;
        if (t == T_STEPS-1)
          out[(size_t)BATCH*T_STEPS*(2*UNITS) + (size_t)b*(2*UNITS) + outcol] = hval;
        _Float16 hf = (_Float16)hval;
        *(_Float16*)(hnx + swz(b, upl)) = hf;
        if (t+1 < T_STEPS)
          __hip_atomic_store(&slc[b*64 + (w*16+l15)],
                             __builtin_bit_cast(unsigned short, hf),
                             __ATOMIC_RELAXED, __HIP_MEMORY_SCOPE_AGENT);
      }
    }
    __syncthreads();

    if (t+1 < T_STEPS){
      if (tid == 192)
        __hip_atomic_store(&flags[(dir*4+g4)*32], (unsigned)(t+1),
                           __ATOMIC_RELAXED, __HIP_MEMORY_SCOPE_AGENT);
#pragma unroll
      for (int j=0;j<4;j++){
        half8 hh;
#pragma unroll
        for (int e=0;e<8;e++) hh[e] = (_Float16)xr[j*8+e];
        *(half8*)((char*)xlds + swz(bx, d0x + j*8)) = hh;
      }
      if (w < 3){
        const int p = w + (w >= g4);
        const unsigned target = (unsigned)(t+1);
        if (spin_ok){
          int sp = 0;
          while (__hip_atomic_load(&flags[(dir*4+p)*32],
                                   __ATOMIC_RELAXED, __HIP_MEMORY_SCOPE_AGENT) < target){
            if (++sp > (1<<22)) { spin_ok = false; break; }
          }
        }
        const ull* src = (const ull*)(slices + (((size_t)((t+1)&1))*8 + dir*4 + p)*2048);
        const int bsl = lane >> 1;
        const int u00 = (lane & 1) * 32;
#pragma unroll
        for (int j=0;j<4;j++){
          ull v0 = __hip_atomic_load(&src[lane*8 + 2*j  ], __ATOMIC_RELAXED, __HIP_MEMORY_SCOPE_AGENT);
          ull v1 = __hip_atomic_load(&src[lane*8 + 2*j+1], __ATOMIC_RELAXED, __HIP_MEMORY_SCOPE_AGENT);
          ull2 vv; vv[0]=v0; vv[1]=v1;
          *(ull2*)(hnx + swz(bsl, p*64 + u00 + j*8)) = vv;
        }
      }
      __syncthreads();
    }
  }
}

extern "C" void kernel_launch(void* const* d_in, const int* in_sizes, int n_in,
                              void* d_out, int out_size, void* d_ws, size_t ws_size,
                              hipStream_t stream) {
  const float* x    = (const float*)d_in[0];
  const float* Wk_f = (const float*)d_in[1];
  const float* Wr_f = (const float*)d_in[2];
  const float* b_f  = (const float*)d_in[3];
  const float* Wk_b = (const float*)d_in[4];
  const float* Wr_b = (const float*)d_in[5];
  const float* b_b  = (const float*)d_in[6];
  float* out = (float*)d_out;

  const size_t XPH = (size_t)2*T_STEPS*COLS4U*BATCH*sizeof(_Float16);  // 64 MiB
  const size_t RPB = (size_t)2*8*4096*8*sizeof(_Float16);              // 1 MiB

  if (ws_size >= XPH + RPB) {
    _Float16* xph = (_Float16*)d_ws;
    _Float16* rp  = (_Float16*)((char*)d_ws + XPH);
    repack<<<256, 256, 0, stream>>>(Wr_f, Wr_b, rp);
    xproj<<<512, 256, 0, stream>>>(x, Wk_f, b_f, Wk_b, b_b, xph);
    bilstm_1cu<<<2, 512, 0, stream>>>(rp, out, xph);
  } else {
    unsigned short* slices = (unsigned short*)d_ws;
    unsigned* flags = (unsigned*)((char*)d_ws + 65536);
    hipMemsetAsync((char*)d_ws + 65536, 0, 1024, stream);
    bilstm_mfma<<<8, 256, 0, stream>>>(x, Wk_f, Wr_f, b_f, Wk_b, Wr_b, b_b,
                                       out, slices, flags);
  }
}